// Round 13
// baseline (273.381 us; speedup 1.0000x reference)
//
#include <hip/hip_runtime.h>
#include <math.h>

#define NDIM 128

// TWO WAVES = ONE BATCH (128-thread blocks, grid = 4096). Lane owns ONE row
// (row = tid); its 64 packed-fp16 u32 Q words live in EXPLICIT AGPRs via
// inline-asm v_accvgpr_write/read with "a" constraints.
//
// Why: rounds 4/10/11/12 proved hipcc's allocator will not keep a 64-word
// invariant tile in VGPRs across nested loops -- it caps VGPRs (64) for an
// occupancy target and spills to scratch (round 11/12: WRITE_SIZE 39 MB,
// dur 218us), ignoring launch_bounds and waves_per_eu(4,4). gfx950's unified
// RF makes AGPRs plain storage: one v_accvgpr_read per use, zero memory
// traffic. Round 10's accidental AGPR overflow already validated this path.
// volatile asm blocks LICM from hoisting the 64 reads out of the CG loop
// (which would recreate the pressure explosion).
//
// Invariants: Q global read EXACTLY once (round 6: re-reads = HBM-bound
// 1.76 GB); broadcast uint4 LDS reads (0 conflicts); fp16-RTN Q operator,
// hi/lo (22-bit) x publish for the outer residual u = Qx - r/x.
// Inner: Jacobi-preconditioned Chronopoulos-Gear CG, tol rz<=1e-5*rz0.
// Outer: exact reference lk/gk logic, per-batch exit lk<1e-5.
// absmax measured 1.22e-4 with this numerics stack (threshold 4.17e-4).

typedef __fp16 h2_t __attribute__((ext_vector_type(2)));
union U32H2 { unsigned int u; h2_t h; };

#if __has_builtin(__builtin_amdgcn_fdot2)
#define FDOT2(a,b,c) __builtin_amdgcn_fdot2((a),(b),(c),false)
#else
#define FDOT2(a,b,c) fmaf((float)(a).x,(float)(b).x, fmaf((float)(a).y,(float)(b).y,(c)))
#endif

__device__ __forceinline__ unsigned int pk_rtn(float x, float y) {
    U32H2 r; r.h.x = (__fp16)x; r.h.y = (__fp16)y; return r.u;   // RTN converts
}

#define DOTG(qu, vu, ACC) { U32H2 _q, _v; _q.u = (qu); _v.u = (vu);            \
    ACC = FDOT2(_q.h, _v.h, ACC); }

// AGPR residency primitives
#define AW(dst, src) asm volatile("v_accvgpr_write_b32 %0, %1" : "=a"(dst) : "v"(src))
#define AR(dst, src) asm volatile("v_accvgpr_read_b32 %0, %1"  : "=v"(dst) : "a"(src))

#define WSUM(v) { v += __shfl_xor(v,32); v += __shfl_xor(v,16);                \
                  v += __shfl_xor(v,8);  v += __shfl_xor(v,4);                 \
                  v += __shfl_xor(v,2);  v += __shfl_xor(v,1); }
#define WMAX(v) { v = fmaxf(v,__shfl_xor(v,32)); v = fmaxf(v,__shfl_xor(v,16));\
                  v = fmaxf(v,__shfl_xor(v,8));  v = fmaxf(v,__shfl_xor(v,4)); \
                  v = fmaxf(v,__shfl_xor(v,2));  v = fmaxf(v,__shfl_xor(v,1)); }

__global__ __launch_bounds__(128)
__attribute__((amdgpu_waves_per_eu(4, 4)))
void rpth_kernel(const float* __restrict__ Q,
                 const float* __restrict__ R,
                 float* __restrict__ out)
{
    const int b    = blockIdx.x;
    const int tid  = threadIdx.x;            // row = tid, 0..127
    const int lane = tid & 63;
    const int wv   = tid >> 6;               // 0..1

    __shared__ __align__(16) unsigned int s_v [64];   // packed CG vector
    __shared__ __align__(16) unsigned int s_xh[64];   // packed x hi
    __shared__ __align__(16) unsigned int s_xl[64];   // packed x lo (x1024)
    __shared__ float s_red[8];

    const size_t qbase = (size_t)b * (NDIM * NDIM);
    const float* prow  = Q + qbase + (size_t)tid * NDIM;

    // ---- 64 AGPR-resident packed Q words for this lane's row ----
#define DECL(c) unsigned ag##c##_0, ag##c##_1, ag##c##_2, ag##c##_3;
    DECL(0)  DECL(1)  DECL(2)  DECL(3)  DECL(4)  DECL(5)  DECL(6)  DECL(7)
    DECL(8)  DECL(9)  DECL(10) DECL(11) DECL(12) DECL(13) DECL(14) DECL(15)
#undef DECL
#define STG(c) {                                                               \
    const float4 _x0 = ((const float4*)prow)[2*(c)];                           \
    const float4 _x1 = ((const float4*)prow)[2*(c)+1];                         \
    const unsigned _p0 = pk_rtn(_x0.x,_x0.y), _p1 = pk_rtn(_x0.z,_x0.w);       \
    const unsigned _p2 = pk_rtn(_x1.x,_x1.y), _p3 = pk_rtn(_x1.z,_x1.w);       \
    AW(ag##c##_0,_p0); AW(ag##c##_1,_p1); AW(ag##c##_2,_p2); AW(ag##c##_3,_p3); }
    STG(0)  STG(1)  STG(2)  STG(3)
    STG(4)  STG(5)  STG(6)  STG(7)
    STG(8)  STG(9)  STG(10) STG(11)
    STG(12) STG(13) STG(14) STG(15)
#undef STG

    const float qd = prow[tid];                       // diagonal Q[row][row]
    const float rv = fabsf(R[(size_t)b * NDIM + tid]);

    float xv = rv / sqrtf(qd);               // x0 = r / sqrt(diag Q)
    const float FLc = 0.36286771f;           // 0.95*(3-sqrt(5))/2
    float lk = FLc + 1.0f;

    // publish x as hi/lo fp16 (adjacent-row pairs; both rows in same wave)
#define PUBX() {                                                               \
    const float _hi = (float)(__fp16)xv;                                       \
    const float _lo = (xv - _hi) * 1024.f;                                     \
    const float _xo = __shfl_xor(xv, 1);                                       \
    const float _lo2= __shfl_xor(_lo, 1);                                      \
    if (!(tid & 1)) {                                                          \
        s_xh[tid >> 1] = pk_rtn(xv,  _xo);                                     \
        s_xl[tid >> 1] = pk_rtn(_lo, _lo2);                                    \
    } }
    PUBX();
    __syncthreads();

    const uint4* vhp = (const uint4*)s_xh;
    const uint4* vlp = (const uint4*)s_xl;
    const uint4* vp  = (const uint4*)s_v;

    for (int it = 0; it < 10; ++it) {
        // ---- outer matvec qx = Qh*xh + Qh*xl/1024 (u accurate ~1e-4) ----
        float ah0=0.f, ah1=0.f, al0=0.f, al1=0.f;
#define MVO(c) { const uint4 _Vh = vhp[c], _Vl = vlp[c];                       \
    unsigned _t0,_t1,_t2,_t3;                                                  \
    AR(_t0,ag##c##_0); AR(_t1,ag##c##_1); AR(_t2,ag##c##_2); AR(_t3,ag##c##_3);\
    DOTG(_t0,_Vh.x,ah0) DOTG(_t1,_Vh.y,ah1)                                    \
    DOTG(_t2,_Vh.z,ah0) DOTG(_t3,_Vh.w,ah1)                                    \
    DOTG(_t0,_Vl.x,al0) DOTG(_t1,_Vl.y,al1)                                    \
    DOTG(_t2,_Vl.z,al0) DOTG(_t3,_Vl.w,al1) }
        MVO(0)  MVO(1)  MVO(2)  MVO(3)  MVO(4)  MVO(5)  MVO(6)  MVO(7)
        MVO(8)  MVO(9)  MVO(10) MVO(11) MVO(12) MVO(13) MVO(14) MVO(15)
#undef MVO
        const float qx = fmaf(al0 + al1, 9.765625e-4f, ah0 + ah1);

        const float rx = rv / xv;
        const float u  = qx - rx;                     // u = Qx - r/x
        const float ex = rx / xv;                     // r/x^2
        const float ih = 1.0f / (qd + ex);            // Jacobi precond

        // ---- umax over block -> sigma (fp16 scaling) ----
        float um = fabsf(u);
        WMAX(um);
        if (lane == 0) s_red[4 + wv] = um;
        __syncthreads();
        const float umax  = fmaxf(s_red[4], s_red[5]);
        const float sigma = 1.0f / fmaxf(umax, 1e-30f);

        // ---- Chronopoulos-Gear PCG on h = Qh + diag(ex), scaled RHS ----
        float rs = u * sigma;
        float z  = rs * ih;
        float dk = 0.f, pp = 0.f, sa = 0.f;
        float alpha = 1.f, rzp = 1.f, rz0v = 0.f, invgam = 1.f;
        {
            const float zo = __shfl_xor(z, 1);
            if (!(tid & 1)) s_v[tid >> 1] = pk_rtn(z, zo);
        }
        __syncthreads();

        for (int cg = 0; cg < 16; ++cg) {
            float a0=0.f, a1=0.f, a2=0.f, a3=0.f;
#define MVI(c) { const uint4 _V = vp[c];                                       \
    unsigned _t0,_t1,_t2,_t3;                                                  \
    AR(_t0,ag##c##_0); AR(_t1,ag##c##_1); AR(_t2,ag##c##_2); AR(_t3,ag##c##_3);\
    DOTG(_t0,_V.x,a0) DOTG(_t1,_V.y,a1)                                        \
    DOTG(_t2,_V.z,a2) DOTG(_t3,_V.w,a3) }
            MVI(0)  MVI(1)  MVI(2)  MVI(3)  MVI(4)  MVI(5)  MVI(6)  MVI(7)
            MVI(8)  MVI(9)  MVI(10) MVI(11) MVI(12) MVI(13) MVI(14) MVI(15)
#undef MVI
            const float w = fmaf(ex, z, ((a0+a1)+(a2+a3)) * invgam);   // h z

            float pr = rs * z;                        // rz partial
            float pd = z  * w;                        // z.hz partial
            WSUM(pr); WSUM(pd);
            if (lane == 0) { s_red[wv] = pr; s_red[2 + wv] = pd; }
            __syncthreads();
            const float rz    = s_red[0] + s_red[1];
            const float delta = s_red[2] + s_red[3];
            if (cg == 0) { rz0v = rz; if (rz0v <= 1e-30f) break; }
            else if (rz <= 1e-5f * rz0v || rz <= 1e-32f) break;   // loose tol
            const float beta = (cg == 0) ? 0.0f : rz / rzp;
            const float pAp  = delta - beta * rz / alpha;
            alpha = rz / pAp;
            pp = fmaf(beta, pp, z);
            sa = fmaf(beta, sa, w);                   // sa = h p (recurrence)
            dk = fmaf( alpha, pp, dk);
            rs = fmaf(-alpha, sa, rs);
            z  = rs * ih;
            rzp = rz;
            const float gam = rsqrtf(rz);             // republish vhat = z*gam
            invgam = sqrtf(rz);
            {
                const float vhat = z * gam;
                const float vo   = __shfl_xor(vhat, 1);
                if (!(tid & 1)) s_v[tid >> 1] = pk_rtn(vhat, vo);
            }
            __syncthreads();
        }
        const float dku = dk * umax;                  // unscale

        // ---- damping / bookkeeping (exact reference logic, fp32) ----
        float gp = fabsf(dku / xv);
        float sp = dku * u;
        WMAX(gp); WSUM(sp);
        if (lane == 0) { s_red[4 + wv] = gp; s_red[6 + wv] = sp; }
        __syncthreads();
        const float gm  = fmaxf(s_red[4], s_red[5]);
        const float lkk = s_red[6] + s_red[7];
        const float gk     = (lk <= FLc) ? 0.0f : gm;
        const float lk_new = sqrtf(fmaxf(lkk, 0.0f));
        xv = xv - dku / (1.0f + gk);
        lk = lk_new;
        if (lk_new < 1e-5f) break;     // remaining reference motion <= 1e-5
        PUBX();
        __syncthreads();
    }

    // ---- normalize: x / (sum|x| + 1e-8) ----
    float sab = fabsf(xv);
    WSUM(sab);
    if (lane == 0) s_red[wv] = sab;
    __syncthreads();
    const float tot = s_red[0] + s_red[1];
    out[(size_t)b * NDIM + tid] = xv / (tot + 1e-8f);
}

extern "C" void kernel_launch(void* const* d_in, const int* in_sizes, int n_in,
                              void* d_out, int out_size, void* d_ws, size_t ws_size,
                              hipStream_t stream) {
    const float* Q = (const float*)d_in[0];
    const float* R = (const float*)d_in[1];
    float* out     = (float*)d_out;
    const int B    = in_sizes[1] / NDIM;   // 4096
    rpth_kernel<<<dim3(B), dim3(128), 0, stream>>>(Q, R, out);
}

// Round 16
// 159.359 us; speedup vs baseline: 1.7155x; 1.7155x over previous
//
#include <hip/hip_runtime.h>
#include <math.h>

#define NDIM 128

// ONE WAVE = ONE BATCH (64-thread blocks, grid = 4096) -- round-10 structure
// (best so far: 177us) with ONE change: all cross-lane reductions switch from
// __shfl_xor chains (ds_bpermute: LDS pipe, ~60-120cy latency, 12 DEPENDENT
// per CG iter = 700-1200cy critical path -- the real stall behind round 10's
// 44% VALUBusy) to DPP reductions (row_shr 1/2/4/8 + row_bcast 15/31 +
// readlane 63): VALU pipe, ~8cy/level, ~60cy total. ~10x latency cut on the
// per-iteration serial chain.
// Round-15 compile fix: dpp_ctrl must be an immediate -> template<int CTRL>.
//
// Everything else identical to round 10: lane owns rows r0=2*lane, r0+1 as
// 128 named u32 of packed fp16 (RTN); zero __syncthreads; CG/x vectors
// published in LDS (wave-synchronous ds ordering via asm memory clobber);
// Q global read EXACTLY once. Numerics validated rounds 9-14: absmax
// 1.22e-4 vs 4.17e-4 threshold (fp16-RTN Q operator, hi/lo 22-bit x publish,
// sigma/gamma fp16 range management, CG tol rz<=1e-5*rz0, exact reference
// lk/gk damping, per-batch exit lk<1e-5).

typedef __fp16 h2_t __attribute__((ext_vector_type(2)));
union U32H2 { unsigned int u; h2_t h; };

#if __has_builtin(__builtin_amdgcn_fdot2)
#define FDOT2(a,b,c) __builtin_amdgcn_fdot2((a),(b),(c),false)
#else
#define FDOT2(a,b,c) fmaf((float)(a).x,(float)(b).x, fmaf((float)(a).y,(float)(b).y,(c)))
#endif

__device__ __forceinline__ unsigned int pk_rtn(float x, float y) {
    U32H2 r; r.h.x = (__fp16)x; r.h.y = (__fp16)y; return r.u;   // RTN converts
}

#define DOTG(qu, vu, ACC) { U32H2 _q, _v; _q.u = (qu); _v.u = (vu);            \
    ACC = FDOT2(_q.h, _v.h, ACC); }

// ---- DPP wave64 reductions (VALU pipe; bound_ctrl=true -> OOB reads give 0) ----
template<int CTRL>
__device__ __forceinline__ float dppadd(float v) {
    const int t = __builtin_amdgcn_update_dpp(0, __float_as_int(v), CTRL, 0xf, 0xf, true);
    return v + __int_as_float(t);
}
template<int CTRL>
__device__ __forceinline__ float dppmax(float v) {   // valid for v >= 0 (OOB gives 0)
    const int t = __builtin_amdgcn_update_dpp(0, __float_as_int(v), CTRL, 0xf, 0xf, true);
    return fmaxf(v, __int_as_float(t));
}
// row_shr:1=0x111 :2=0x112 :4=0x114 :8=0x118, row_bcast15=0x142, row_bcast31=0x143
#define WSUM(v) { v=dppadd<0x111>(v); v=dppadd<0x112>(v); v=dppadd<0x114>(v);  \
                  v=dppadd<0x118>(v); v=dppadd<0x142>(v); v=dppadd<0x143>(v);  \
                  v=__int_as_float(__builtin_amdgcn_readlane(__float_as_int(v),63)); }
#define WMAX(v) { v=dppmax<0x111>(v); v=dppmax<0x112>(v); v=dppmax<0x114>(v);  \
                  v=dppmax<0x118>(v); v=dppmax<0x142>(v); v=dppmax<0x143>(v);  \
                  v=__int_as_float(__builtin_amdgcn_readlane(__float_as_int(v),63)); }

__global__ __launch_bounds__(64, 2)
void rpth_kernel(const float* __restrict__ Q,
                 const float* __restrict__ R,
                 float* __restrict__ out)
{
    const int b    = blockIdx.x;
    const int lane = threadIdx.x;            // 0..63
    const int r0   = 2 * lane;

    __shared__ __align__(16) unsigned int s_v [64];   // packed CG vector
    __shared__ __align__(16) unsigned int s_xh[64];   // packed x hi
    __shared__ __align__(16) unsigned int s_xl[64];   // packed x lo (x1024)

    const size_t qbase = (size_t)b * (NDIM * NDIM);
    const float* p0 = Q + qbase + (size_t)r0 * NDIM;
    const float* p1 = p0 + NDIM;

    // ---- 128 named u32 scalars: packed fp16 Q rows r0 (a*) and r0+1 (b*) ----
#define DECL(c) unsigned a##c##_0,a##c##_1,a##c##_2,a##c##_3,                  \
                         b##c##_0,b##c##_1,b##c##_2,b##c##_3;
    DECL(0)  DECL(1)  DECL(2)  DECL(3)  DECL(4)  DECL(5)  DECL(6)  DECL(7)
    DECL(8)  DECL(9)  DECL(10) DECL(11) DECL(12) DECL(13) DECL(14) DECL(15)
#undef DECL
#define STG(c) {                                                               \
    const float4 _x0 = ((const float4*)p0)[2*(c)];                             \
    const float4 _x1 = ((const float4*)p0)[2*(c)+1];                           \
    const float4 _y0 = ((const float4*)p1)[2*(c)];                             \
    const float4 _y1 = ((const float4*)p1)[2*(c)+1];                           \
    a##c##_0 = pk_rtn(_x0.x,_x0.y); a##c##_1 = pk_rtn(_x0.z,_x0.w);            \
    a##c##_2 = pk_rtn(_x1.x,_x1.y); a##c##_3 = pk_rtn(_x1.z,_x1.w);            \
    b##c##_0 = pk_rtn(_y0.x,_y0.y); b##c##_1 = pk_rtn(_y0.z,_y0.w);            \
    b##c##_2 = pk_rtn(_y1.x,_y1.y); b##c##_3 = pk_rtn(_y1.z,_y1.w); }
    STG(0)  STG(1)  STG(2)  STG(3)  STG(4)  STG(5)  STG(6)  STG(7)
    STG(8)  STG(9)  STG(10) STG(11) STG(12) STG(13) STG(14) STG(15)
#undef STG

    const float qd0 = Q[qbase + (size_t)r0 * (NDIM + 1)];
    const float qd1 = Q[qbase + (size_t)(r0 + 1) * (NDIM + 1)];
    const float2 rr = ((const float2*)(R + (size_t)b * NDIM))[lane];
    const float rv0 = fabsf(rr.x), rv1 = fabsf(rr.y);

    float xv0 = rv0 / sqrtf(qd0);            // x0 = r / sqrt(diag Q)
    float xv1 = rv1 / sqrtf(qd1);

    const float FLc = 0.36286771f;           // 0.95*(3-sqrt(5))/2
    float lk = FLc + 1.0f;

#define PUBX() {                                                               \
    const float _h0 = (float)(__fp16)xv0, _h1 = (float)(__fp16)xv1;            \
    s_xh[lane] = pk_rtn(xv0, xv1);                                             \
    s_xl[lane] = pk_rtn((xv0 - _h0) * 1024.f, (xv1 - _h1) * 1024.f);           \
    asm volatile("" ::: "memory"); }
    PUBX();

    const uint4* vhp = (const uint4*)s_xh;
    const uint4* vlp = (const uint4*)s_xl;
    const uint4* vp  = (const uint4*)s_v;

    for (int it = 0; it < 10; ++it) {
        // ---- outer matvec qx = Qh*xh + Qh*xl/1024 (u accurate ~1e-4) ----
        float ah0=0.f, ah1=0.f, al0=0.f, al1=0.f;
#define MVO(c) { const uint4 _Vh = vhp[c], _Vl = vlp[c];                       \
    DOTG(a##c##_0,_Vh.x,ah0) DOTG(a##c##_1,_Vh.y,ah0)                          \
    DOTG(a##c##_2,_Vh.z,ah0) DOTG(a##c##_3,_Vh.w,ah0)                          \
    DOTG(b##c##_0,_Vh.x,ah1) DOTG(b##c##_1,_Vh.y,ah1)                          \
    DOTG(b##c##_2,_Vh.z,ah1) DOTG(b##c##_3,_Vh.w,ah1)                          \
    DOTG(a##c##_0,_Vl.x,al0) DOTG(a##c##_1,_Vl.y,al0)                          \
    DOTG(a##c##_2,_Vl.z,al0) DOTG(a##c##_3,_Vl.w,al0)                          \
    DOTG(b##c##_0,_Vl.x,al1) DOTG(b##c##_1,_Vl.y,al1)                          \
    DOTG(b##c##_2,_Vl.z,al1) DOTG(b##c##_3,_Vl.w,al1) }
        MVO(0)  MVO(1)  MVO(2)  MVO(3)  MVO(4)  MVO(5)  MVO(6)  MVO(7)
        MVO(8)  MVO(9)  MVO(10) MVO(11) MVO(12) MVO(13) MVO(14) MVO(15)
#undef MVO
        const float qx0 = fmaf(al0, 9.765625e-4f, ah0);
        const float qx1 = fmaf(al1, 9.765625e-4f, ah1);

        const float rx0 = rv0 / xv0,  rx1 = rv1 / xv1;
        const float u0  = qx0 - rx0,  u1  = qx1 - rx1;    // u = Qx - r/x
        const float ex0 = rx0 / xv0,  ex1 = rx1 / xv1;    // r/x^2
        const float ih0 = 1.0f / (qd0 + ex0);             // Jacobi precond
        const float ih1 = 1.0f / (qd1 + ex1);

        float umax = fmaxf(fabsf(u0), fabsf(u1));
        WMAX(umax);
        const float sigma = 1.0f / fmaxf(umax, 1e-30f);

        // ---- Chronopoulos-Gear PCG on h = Qh + diag(extra), scaled RHS ----
        float rs0 = u0 * sigma, rs1 = u1 * sigma;
        float z0  = rs0 * ih0,  z1  = rs1 * ih1;
        float dk0 = 0.f, dk1 = 0.f, pp0 = 0.f, pp1 = 0.f, sa0 = 0.f, sa1 = 0.f;
        float alpha = 1.f, rzp = 1.f, rz0v = 0.f, invgam = 1.f;
        s_v[lane] = pk_rtn(z0, z1);
        asm volatile("" ::: "memory");

        for (int cg = 0; cg < 16; ++cg) {
            float ac0a=0.f, ac0b=0.f, ac1a=0.f, ac1b=0.f;
#define MVI(c,X0,X1) { const uint4 _V = vp[c];                                 \
    DOTG(a##c##_0,_V.x,X0) DOTG(a##c##_1,_V.y,X0)                              \
    DOTG(a##c##_2,_V.z,X0) DOTG(a##c##_3,_V.w,X0)                              \
    DOTG(b##c##_0,_V.x,X1) DOTG(b##c##_1,_V.y,X1)                              \
    DOTG(b##c##_2,_V.z,X1) DOTG(b##c##_3,_V.w,X1) }
            MVI(0,ac0a,ac1a)  MVI(1,ac0b,ac1b)  MVI(2,ac0a,ac1a)  MVI(3,ac0b,ac1b)
            MVI(4,ac0a,ac1a)  MVI(5,ac0b,ac1b)  MVI(6,ac0a,ac1a)  MVI(7,ac0b,ac1b)
            MVI(8,ac0a,ac1a)  MVI(9,ac0b,ac1b)  MVI(10,ac0a,ac1a) MVI(11,ac0b,ac1b)
            MVI(12,ac0a,ac1a) MVI(13,ac0b,ac1b) MVI(14,ac0a,ac1a) MVI(15,ac0b,ac1b)
#undef MVI
            const float w0 = fmaf(ex0, z0, (ac0a + ac0b) * invgam);  // h z
            const float w1 = fmaf(ex1, z1, (ac1a + ac1b) * invgam);

            float pr = fmaf(rs0, z0, rs1 * z1);      // rz
            float pd = fmaf(z0,  w0, z1  * w1);      // z.hz
            WSUM(pr); WSUM(pd);
            if (cg == 0) { rz0v = pr; if (rz0v <= 1e-30f) break; }
            else if (pr <= 1e-5f * rz0v || pr <= 1e-32f) break;   // loose tol
            const float beta = (cg == 0) ? 0.0f : pr / rzp;
            const float pAp  = pd - beta * pr / alpha;
            alpha = pr / pAp;
            pp0 = fmaf(beta, pp0, z0);  pp1 = fmaf(beta, pp1, z1);
            sa0 = fmaf(beta, sa0, w0);  sa1 = fmaf(beta, sa1, w1);   // h p
            dk0 = fmaf(alpha, pp0, dk0); dk1 = fmaf(alpha, pp1, dk1);
            rs0 = fmaf(-alpha, sa0, rs0); rs1 = fmaf(-alpha, sa1, rs1);
            z0 = rs0 * ih0;  z1 = rs1 * ih1;
            rzp = pr;
            const float gam = rsqrtf(pr);            // republish vhat = z*gam
            invgam = sqrtf(pr);
            s_v[lane] = pk_rtn(z0 * gam, z1 * gam);
            asm volatile("" ::: "memory");
        }
        const float dku0 = dk0 * umax, dku1 = dk1 * umax;   // unscale

        // ---- damping / bookkeeping (exact reference logic, fp32) ----
        float gp = fmaxf(fabsf(dku0 / xv0), fabsf(dku1 / xv1));
        float sp = fmaf(dku0, u0, dku1 * u1);
        WMAX(gp); WSUM(sp);
        const float gk     = (lk <= FLc) ? 0.0f : gp;
        const float lk_new = sqrtf(fmaxf(sp, 0.0f));
        const float damp   = 1.0f / (1.0f + gk);
        xv0 -= dku0 * damp;
        xv1 -= dku1 * damp;
        lk = lk_new;
        if (lk_new < 1e-5f) break;     // remaining reference motion <= 1e-5
        PUBX();
    }

    // ---- normalize: x / (sum|x| + 1e-8) ----
    float sab = fabsf(xv0) + fabsf(xv1);
    WSUM(sab);
    const float inv = 1.0f / (sab + 1e-8f);
    ((float2*)(out + (size_t)b * NDIM))[lane] = make_float2(xv0 * inv, xv1 * inv);
}

extern "C" void kernel_launch(void* const* d_in, const int* in_sizes, int n_in,
                              void* d_out, int out_size, void* d_ws, size_t ws_size,
                              hipStream_t stream) {
    const float* Q = (const float*)d_in[0];
    const float* R = (const float*)d_in[1];
    float* out     = (float*)d_out;
    const int B    = in_sizes[1] / NDIM;   // 4096
    rpth_kernel<<<dim3(B), dim3(64), 0, stream>>>(Q, R, out);
}

// Round 17
// 136.627 us; speedup vs baseline: 2.0009x; 1.1664x over previous
//
#include <hip/hip_runtime.h>
#include <math.h>

#define NDIM 128

// ONE WAVE = ONE BATCH (64-thread blocks, grid = 4096). Round-16 structure
// (DPP reductions, 159us) with three aligned algorithmic cuts:
//  1. CG tol rz <= 1e-4*rz0 (was 1e-5): inexact-Newton eta~1e-2, same outer
//     trajectory scale, ~25% fewer inner iters.
//  2. gamma republish normalization DROPPED (sigma=1/max|u| kept): published
//     z stays in [3e-3, 1] -- normal fp16 -- so rsqrt/sqrt/mult leave the
//     per-CG-iter serial scalar chain.
//  3. Per-batch exit lk < 1e-4 (was 1e-5): remaining motion <= 1e-4 ->
//     output shift ~4e-6 after /sum|x|; shortens the straggler tail.
//
// Carried invariants: lane owns rows r0=2*lane,r0+1 as 128 named u32 of
// packed fp16 RTN (no arrays/aggregates -> VGPR-resident, VGPR=124); zero
// __syncthreads; DPP row_shr/row_bcast reductions (VALU pipe, round-16 win);
// CG/x vectors published in LDS (wave-synchronous ds ordering, asm clobber);
// Q global read EXACTLY once; outer residual u = Qh*(x hi+lo) in fp32.
// Inner: Jacobi-preconditioned Chronopoulos-Gear CG. Outer: exact reference
// lk/gk damping. absmax was 1.22e-4 at tol 1e-5 (threshold 4.17e-4).

typedef __fp16 h2_t __attribute__((ext_vector_type(2)));
union U32H2 { unsigned int u; h2_t h; };

#if __has_builtin(__builtin_amdgcn_fdot2)
#define FDOT2(a,b,c) __builtin_amdgcn_fdot2((a),(b),(c),false)
#else
#define FDOT2(a,b,c) fmaf((float)(a).x,(float)(b).x, fmaf((float)(a).y,(float)(b).y,(c)))
#endif

__device__ __forceinline__ unsigned int pk_rtn(float x, float y) {
    U32H2 r; r.h.x = (__fp16)x; r.h.y = (__fp16)y; return r.u;   // RTN converts
}

#define DOTG(qu, vu, ACC) { U32H2 _q, _v; _q.u = (qu); _v.u = (vu);            \
    ACC = FDOT2(_q.h, _v.h, ACC); }

// ---- DPP wave64 reductions (VALU pipe; bound_ctrl=true -> OOB reads give 0) ----
template<int CTRL>
__device__ __forceinline__ float dppadd(float v) {
    const int t = __builtin_amdgcn_update_dpp(0, __float_as_int(v), CTRL, 0xf, 0xf, true);
    return v + __int_as_float(t);
}
template<int CTRL>
__device__ __forceinline__ float dppmax(float v) {   // valid for v >= 0 (OOB gives 0)
    const int t = __builtin_amdgcn_update_dpp(0, __float_as_int(v), CTRL, 0xf, 0xf, true);
    return fmaxf(v, __int_as_float(t));
}
// row_shr:1=0x111 :2=0x112 :4=0x114 :8=0x118, row_bcast15=0x142, row_bcast31=0x143
#define WSUM(v) { v=dppadd<0x111>(v); v=dppadd<0x112>(v); v=dppadd<0x114>(v);  \
                  v=dppadd<0x118>(v); v=dppadd<0x142>(v); v=dppadd<0x143>(v);  \
                  v=__int_as_float(__builtin_amdgcn_readlane(__float_as_int(v),63)); }
#define WMAX(v) { v=dppmax<0x111>(v); v=dppmax<0x112>(v); v=dppmax<0x114>(v);  \
                  v=dppmax<0x118>(v); v=dppmax<0x142>(v); v=dppmax<0x143>(v);  \
                  v=__int_as_float(__builtin_amdgcn_readlane(__float_as_int(v),63)); }

__global__ __launch_bounds__(64, 2)
void rpth_kernel(const float* __restrict__ Q,
                 const float* __restrict__ R,
                 float* __restrict__ out)
{
    const int b    = blockIdx.x;
    const int lane = threadIdx.x;            // 0..63
    const int r0   = 2 * lane;

    __shared__ __align__(16) unsigned int s_v [64];   // packed CG vector
    __shared__ __align__(16) unsigned int s_xh[64];   // packed x hi
    __shared__ __align__(16) unsigned int s_xl[64];   // packed x lo (x1024)

    const size_t qbase = (size_t)b * (NDIM * NDIM);
    const float* p0 = Q + qbase + (size_t)r0 * NDIM;
    const float* p1 = p0 + NDIM;

    // ---- 128 named u32 scalars: packed fp16 Q rows r0 (a*) and r0+1 (b*) ----
#define DECL(c) unsigned a##c##_0,a##c##_1,a##c##_2,a##c##_3,                  \
                         b##c##_0,b##c##_1,b##c##_2,b##c##_3;
    DECL(0)  DECL(1)  DECL(2)  DECL(3)  DECL(4)  DECL(5)  DECL(6)  DECL(7)
    DECL(8)  DECL(9)  DECL(10) DECL(11) DECL(12) DECL(13) DECL(14) DECL(15)
#undef DECL
#define STG(c) {                                                               \
    const float4 _x0 = ((const float4*)p0)[2*(c)];                             \
    const float4 _x1 = ((const float4*)p0)[2*(c)+1];                           \
    const float4 _y0 = ((const float4*)p1)[2*(c)];                             \
    const float4 _y1 = ((const float4*)p1)[2*(c)+1];                           \
    a##c##_0 = pk_rtn(_x0.x,_x0.y); a##c##_1 = pk_rtn(_x0.z,_x0.w);            \
    a##c##_2 = pk_rtn(_x1.x,_x1.y); a##c##_3 = pk_rtn(_x1.z,_x1.w);            \
    b##c##_0 = pk_rtn(_y0.x,_y0.y); b##c##_1 = pk_rtn(_y0.z,_y0.w);            \
    b##c##_2 = pk_rtn(_y1.x,_y1.y); b##c##_3 = pk_rtn(_y1.z,_y1.w); }
    STG(0)  STG(1)  STG(2)  STG(3)  STG(4)  STG(5)  STG(6)  STG(7)
    STG(8)  STG(9)  STG(10) STG(11) STG(12) STG(13) STG(14) STG(15)
#undef STG

    const float qd0 = Q[qbase + (size_t)r0 * (NDIM + 1)];
    const float qd1 = Q[qbase + (size_t)(r0 + 1) * (NDIM + 1)];
    const float2 rr = ((const float2*)(R + (size_t)b * NDIM))[lane];
    const float rv0 = fabsf(rr.x), rv1 = fabsf(rr.y);

    float xv0 = rv0 / sqrtf(qd0);            // x0 = r / sqrt(diag Q)
    float xv1 = rv1 / sqrtf(qd1);

    const float FLc = 0.36286771f;           // 0.95*(3-sqrt(5))/2
    float lk = FLc + 1.0f;

#define PUBX() {                                                               \
    const float _h0 = (float)(__fp16)xv0, _h1 = (float)(__fp16)xv1;            \
    s_xh[lane] = pk_rtn(xv0, xv1);                                             \
    s_xl[lane] = pk_rtn((xv0 - _h0) * 1024.f, (xv1 - _h1) * 1024.f);           \
    asm volatile("" ::: "memory"); }
    PUBX();

    const uint4* vhp = (const uint4*)s_xh;
    const uint4* vlp = (const uint4*)s_xl;
    const uint4* vp  = (const uint4*)s_v;

    for (int it = 0; it < 10; ++it) {
        // ---- outer matvec qx = Qh*xh + Qh*xl/1024 (u accurate ~1e-4) ----
        float ah0=0.f, ah1=0.f, al0=0.f, al1=0.f;
#define MVO(c) { const uint4 _Vh = vhp[c], _Vl = vlp[c];                       \
    DOTG(a##c##_0,_Vh.x,ah0) DOTG(a##c##_1,_Vh.y,ah0)                          \
    DOTG(a##c##_2,_Vh.z,ah0) DOTG(a##c##_3,_Vh.w,ah0)                          \
    DOTG(b##c##_0,_Vh.x,ah1) DOTG(b##c##_1,_Vh.y,ah1)                          \
    DOTG(b##c##_2,_Vh.z,ah1) DOTG(b##c##_3,_Vh.w,ah1)                          \
    DOTG(a##c##_0,_Vl.x,al0) DOTG(a##c##_1,_Vl.y,al0)                          \
    DOTG(a##c##_2,_Vl.z,al0) DOTG(a##c##_3,_Vl.w,al0)                          \
    DOTG(b##c##_0,_Vl.x,al1) DOTG(b##c##_1,_Vl.y,al1)                          \
    DOTG(b##c##_2,_Vl.z,al1) DOTG(b##c##_3,_Vl.w,al1) }
        MVO(0)  MVO(1)  MVO(2)  MVO(3)  MVO(4)  MVO(5)  MVO(6)  MVO(7)
        MVO(8)  MVO(9)  MVO(10) MVO(11) MVO(12) MVO(13) MVO(14) MVO(15)
#undef MVO
        const float qx0 = fmaf(al0, 9.765625e-4f, ah0);
        const float qx1 = fmaf(al1, 9.765625e-4f, ah1);

        const float rx0 = rv0 / xv0,  rx1 = rv1 / xv1;
        const float u0  = qx0 - rx0,  u1  = qx1 - rx1;    // u = Qx - r/x
        const float ex0 = rx0 / xv0,  ex1 = rx1 / xv1;    // r/x^2
        const float ih0 = 1.0f / (qd0 + ex0);             // Jacobi precond
        const float ih1 = 1.0f / (qd1 + ex1);

        float umax = fmaxf(fabsf(u0), fabsf(u1));
        WMAX(umax);
        const float sigma = 1.0f / fmaxf(umax, 1e-30f);

        // ---- Chronopoulos-Gear PCG on h = Qh + diag(extra), scaled RHS ----
        // sigma-scaled: published z stays in ~[3e-3, 1] (normal fp16) through
        // the whole solve at tol 1e-4 -> no per-iter gamma renorm needed.
        float rs0 = u0 * sigma, rs1 = u1 * sigma;
        float z0  = rs0 * ih0,  z1  = rs1 * ih1;
        float dk0 = 0.f, dk1 = 0.f, pp0 = 0.f, pp1 = 0.f, sa0 = 0.f, sa1 = 0.f;
        float alpha = 1.f, rzp = 1.f, rz0v = 0.f;
        s_v[lane] = pk_rtn(z0, z1);
        asm volatile("" ::: "memory");

        for (int cg = 0; cg < 16; ++cg) {
            float ac0a=0.f, ac0b=0.f, ac1a=0.f, ac1b=0.f;
#define MVI(c,X0,X1) { const uint4 _V = vp[c];                                 \
    DOTG(a##c##_0,_V.x,X0) DOTG(a##c##_1,_V.y,X0)                              \
    DOTG(a##c##_2,_V.z,X0) DOTG(a##c##_3,_V.w,X0)                              \
    DOTG(b##c##_0,_V.x,X1) DOTG(b##c##_1,_V.y,X1)                              \
    DOTG(b##c##_2,_V.z,X1) DOTG(b##c##_3,_V.w,X1) }
            MVI(0,ac0a,ac1a)  MVI(1,ac0b,ac1b)  MVI(2,ac0a,ac1a)  MVI(3,ac0b,ac1b)
            MVI(4,ac0a,ac1a)  MVI(5,ac0b,ac1b)  MVI(6,ac0a,ac1a)  MVI(7,ac0b,ac1b)
            MVI(8,ac0a,ac1a)  MVI(9,ac0b,ac1b)  MVI(10,ac0a,ac1a) MVI(11,ac0b,ac1b)
            MVI(12,ac0a,ac1a) MVI(13,ac0b,ac1b) MVI(14,ac0a,ac1a) MVI(15,ac0b,ac1b)
#undef MVI
            const float w0 = fmaf(ex0, z0, ac0a + ac0b);  // h z
            const float w1 = fmaf(ex1, z1, ac1a + ac1b);

            float pr = fmaf(rs0, z0, rs1 * z1);      // rz
            float pd = fmaf(z0,  w0, z1  * w1);      // z.hz
            WSUM(pr); WSUM(pd);
            if (cg == 0) { rz0v = pr; if (rz0v <= 1e-30f) break; }
            else if (pr <= 1e-4f * rz0v || pr <= 1e-32f) break;   // looser tol
            const float beta = (cg == 0) ? 0.0f : pr / rzp;
            const float pAp  = pd - beta * pr / alpha;
            alpha = pr / pAp;
            pp0 = fmaf(beta, pp0, z0);  pp1 = fmaf(beta, pp1, z1);
            sa0 = fmaf(beta, sa0, w0);  sa1 = fmaf(beta, sa1, w1);   // h p
            dk0 = fmaf(alpha, pp0, dk0); dk1 = fmaf(alpha, pp1, dk1);
            rs0 = fmaf(-alpha, sa0, rs0); rs1 = fmaf(-alpha, sa1, rs1);
            z0 = rs0 * ih0;  z1 = rs1 * ih1;
            rzp = pr;
            s_v[lane] = pk_rtn(z0, z1);              // republish (no gamma)
            asm volatile("" ::: "memory");
        }
        const float dku0 = dk0 * umax, dku1 = dk1 * umax;   // unscale

        // ---- damping / bookkeeping (exact reference logic, fp32) ----
        float gp = fmaxf(fabsf(dku0 / xv0), fabsf(dku1 / xv1));
        float sp = fmaf(dku0, u0, dku1 * u1);
        WMAX(gp); WSUM(sp);
        const float gk     = (lk <= FLc) ? 0.0f : gp;
        const float lk_new = sqrtf(fmaxf(sp, 0.0f));
        const float damp   = 1.0f / (1.0f + gk);
        xv0 -= dku0 * damp;
        xv1 -= dku1 * damp;
        lk = lk_new;
        if (lk_new < 1e-4f) break;     // remaining motion <= 1e-4 -> out ~4e-6
        PUBX();
    }

    // ---- normalize: x / (sum|x| + 1e-8) ----
    float sab = fabsf(xv0) + fabsf(xv1);
    WSUM(sab);
    const float inv = 1.0f / (sab + 1e-8f);
    ((float2*)(out + (size_t)b * NDIM))[lane] = make_float2(xv0 * inv, xv1 * inv);
}

extern "C" void kernel_launch(void* const* d_in, const int* in_sizes, int n_in,
                              void* d_out, int out_size, void* d_ws, size_t ws_size,
                              hipStream_t stream) {
    const float* Q = (const float*)d_in[0];
    const float* R = (const float*)d_in[1];
    float* out     = (float*)d_out;
    const int B    = in_sizes[1] / NDIM;   // 4096
    rpth_kernel<<<dim3(B), dim3(64), 0, stream>>>(Q, R, out);
}

// Round 18
// 88.980 us; speedup vs baseline: 3.0724x; 1.5355x over previous
//
#include <hip/hip_runtime.h>
#include <math.h>

#define NDIM 128

// ONE WAVE = ONE BATCH (64-thread blocks, grid = 4096). Round-17 base
// (136us, DPP reductions, loose tols) with two algebraic cuts:
//  1. OUTER MATVEC ELIMINATED (except it=0): at CG exit h*dku = u - umax*rs
//     exactly (Chronopoulos residual invariant), so Qh*dku = u - umax*rs -
//     ex.*dku -- all lane-local. qx maintained by recurrence
//     qx -= damp*(u - umax*rs - ex*dku): 256 dot2/outer-iter -> 6 FMAs,
//     and the x hi/lo LDS publish disappears. Same Qh operator as CG ->
//     same fixed point; fp32 drift over <=10 outers ~1e-6.
//  2. Eisenstat-Walker forcing eta = clamp(lk, 0.01, 0.3), rz-tol =
//     eta^2*rz0: early (heavily damped) Newton steps use ~3 CG iters,
//     final steps keep eta=0.01 (= round 17's endpoint accuracy).
//
// Carried invariants: lane owns rows r0=2*lane,r0+1 as 128 named u32 of
// packed fp16 RTN (VGPR-resident, VGPR=124); zero __syncthreads; DPP
// row_shr/row_bcast reductions (VALU pipe); CG vector published in LDS
// (wave-synchronous ds ordering, asm clobber); Q global read EXACTLY once.
// absmax floor 1.22e-4 = fp16-Q operator error (threshold 4.17e-4).

typedef __fp16 h2_t __attribute__((ext_vector_type(2)));
union U32H2 { unsigned int u; h2_t h; };

#if __has_builtin(__builtin_amdgcn_fdot2)
#define FDOT2(a,b,c) __builtin_amdgcn_fdot2((a),(b),(c),false)
#else
#define FDOT2(a,b,c) fmaf((float)(a).x,(float)(b).x, fmaf((float)(a).y,(float)(b).y,(c)))
#endif

__device__ __forceinline__ unsigned int pk_rtn(float x, float y) {
    U32H2 r; r.h.x = (__fp16)x; r.h.y = (__fp16)y; return r.u;   // RTN converts
}

#define DOTG(qu, vu, ACC) { U32H2 _q, _v; _q.u = (qu); _v.u = (vu);            \
    ACC = FDOT2(_q.h, _v.h, ACC); }

// ---- DPP wave64 reductions (VALU pipe; bound_ctrl=true -> OOB reads give 0) ----
template<int CTRL>
__device__ __forceinline__ float dppadd(float v) {
    const int t = __builtin_amdgcn_update_dpp(0, __float_as_int(v), CTRL, 0xf, 0xf, true);
    return v + __int_as_float(t);
}
template<int CTRL>
__device__ __forceinline__ float dppmax(float v) {   // valid for v >= 0 (OOB gives 0)
    const int t = __builtin_amdgcn_update_dpp(0, __float_as_int(v), CTRL, 0xf, 0xf, true);
    return fmaxf(v, __int_as_float(t));
}
// row_shr:1=0x111 :2=0x112 :4=0x114 :8=0x118, row_bcast15=0x142, row_bcast31=0x143
#define WSUM(v) { v=dppadd<0x111>(v); v=dppadd<0x112>(v); v=dppadd<0x114>(v);  \
                  v=dppadd<0x118>(v); v=dppadd<0x142>(v); v=dppadd<0x143>(v);  \
                  v=__int_as_float(__builtin_amdgcn_readlane(__float_as_int(v),63)); }
#define WMAX(v) { v=dppmax<0x111>(v); v=dppmax<0x112>(v); v=dppmax<0x114>(v);  \
                  v=dppmax<0x118>(v); v=dppmax<0x142>(v); v=dppmax<0x143>(v);  \
                  v=__int_as_float(__builtin_amdgcn_readlane(__float_as_int(v),63)); }

__global__ __launch_bounds__(64, 2)
void rpth_kernel(const float* __restrict__ Q,
                 const float* __restrict__ R,
                 float* __restrict__ out)
{
    const int b    = blockIdx.x;
    const int lane = threadIdx.x;            // 0..63
    const int r0   = 2 * lane;

    __shared__ __align__(16) unsigned int s_v [64];   // packed CG vector
    __shared__ __align__(16) unsigned int s_xh[64];   // packed x0 hi (it=0 only)
    __shared__ __align__(16) unsigned int s_xl[64];   // packed x0 lo (it=0 only)

    const size_t qbase = (size_t)b * (NDIM * NDIM);
    const float* p0 = Q + qbase + (size_t)r0 * NDIM;
    const float* p1 = p0 + NDIM;

    // ---- 128 named u32 scalars: packed fp16 Q rows r0 (a*) and r0+1 (b*) ----
#define DECL(c) unsigned a##c##_0,a##c##_1,a##c##_2,a##c##_3,                  \
                         b##c##_0,b##c##_1,b##c##_2,b##c##_3;
    DECL(0)  DECL(1)  DECL(2)  DECL(3)  DECL(4)  DECL(5)  DECL(6)  DECL(7)
    DECL(8)  DECL(9)  DECL(10) DECL(11) DECL(12) DECL(13) DECL(14) DECL(15)
#undef DECL
#define STG(c) {                                                               \
    const float4 _x0 = ((const float4*)p0)[2*(c)];                             \
    const float4 _x1 = ((const float4*)p0)[2*(c)+1];                           \
    const float4 _y0 = ((const float4*)p1)[2*(c)];                             \
    const float4 _y1 = ((const float4*)p1)[2*(c)+1];                           \
    a##c##_0 = pk_rtn(_x0.x,_x0.y); a##c##_1 = pk_rtn(_x0.z,_x0.w);            \
    a##c##_2 = pk_rtn(_x1.x,_x1.y); a##c##_3 = pk_rtn(_x1.z,_x1.w);            \
    b##c##_0 = pk_rtn(_y0.x,_y0.y); b##c##_1 = pk_rtn(_y0.z,_y0.w);            \
    b##c##_2 = pk_rtn(_y1.x,_y1.y); b##c##_3 = pk_rtn(_y1.z,_y1.w); }
    STG(0)  STG(1)  STG(2)  STG(3)  STG(4)  STG(5)  STG(6)  STG(7)
    STG(8)  STG(9)  STG(10) STG(11) STG(12) STG(13) STG(14) STG(15)
#undef STG

    const float qd0 = Q[qbase + (size_t)r0 * (NDIM + 1)];
    const float qd1 = Q[qbase + (size_t)(r0 + 1) * (NDIM + 1)];
    const float2 rr = ((const float2*)(R + (size_t)b * NDIM))[lane];
    const float rv0 = fabsf(rr.x), rv1 = fabsf(rr.y);

    float xv0 = rv0 / sqrtf(qd0);            // x0 = r / sqrt(diag Q)
    float xv1 = rv1 / sqrtf(qd1);

    const float FLc = 0.36286771f;           // 0.95*(3-sqrt(5))/2
    float lk = FLc + 1.0f;

    // ---- one-time publish of x0 (hi/lo) and one-time outer matvec Qh*x0 ----
    {
        const float _h0 = (float)(__fp16)xv0, _h1 = (float)(__fp16)xv1;
        s_xh[lane] = pk_rtn(xv0, xv1);
        s_xl[lane] = pk_rtn((xv0 - _h0) * 1024.f, (xv1 - _h1) * 1024.f);
        asm volatile("" ::: "memory");
    }
    const uint4* vhp = (const uint4*)s_xh;
    const uint4* vlp = (const uint4*)s_xl;
    const uint4* vp  = (const uint4*)s_v;

    float qx0, qx1;
    {
        float ah0=0.f, ah1=0.f, al0=0.f, al1=0.f;
#define MVO(c) { const uint4 _Vh = vhp[c], _Vl = vlp[c];                       \
    DOTG(a##c##_0,_Vh.x,ah0) DOTG(a##c##_1,_Vh.y,ah0)                          \
    DOTG(a##c##_2,_Vh.z,ah0) DOTG(a##c##_3,_Vh.w,ah0)                          \
    DOTG(b##c##_0,_Vh.x,ah1) DOTG(b##c##_1,_Vh.y,ah1)                          \
    DOTG(b##c##_2,_Vh.z,ah1) DOTG(b##c##_3,_Vh.w,ah1)                          \
    DOTG(a##c##_0,_Vl.x,al0) DOTG(a##c##_1,_Vl.y,al0)                          \
    DOTG(a##c##_2,_Vl.z,al0) DOTG(a##c##_3,_Vl.w,al0)                          \
    DOTG(b##c##_0,_Vl.x,al1) DOTG(b##c##_1,_Vl.y,al1)                          \
    DOTG(b##c##_2,_Vl.z,al1) DOTG(b##c##_3,_Vl.w,al1) }
        MVO(0)  MVO(1)  MVO(2)  MVO(3)  MVO(4)  MVO(5)  MVO(6)  MVO(7)
        MVO(8)  MVO(9)  MVO(10) MVO(11) MVO(12) MVO(13) MVO(14) MVO(15)
#undef MVO
        qx0 = fmaf(al0, 9.765625e-4f, ah0);
        qx1 = fmaf(al1, 9.765625e-4f, ah1);
    }

    for (int it = 0; it < 10; ++it) {
        const float rx0 = rv0 / xv0,  rx1 = rv1 / xv1;
        const float u0  = qx0 - rx0,  u1  = qx1 - rx1;    // u = Qh x - r/x
        const float ex0 = rx0 / xv0,  ex1 = rx1 / xv1;    // r/x^2
        const float ih0 = 1.0f / (qd0 + ex0);             // Jacobi precond
        const float ih1 = 1.0f / (qd1 + ex1);

        float umax = fmaxf(fabsf(u0), fabsf(u1));
        WMAX(umax);
        const float sigma = 1.0f / fmaxf(umax, 1e-30f);

        // Eisenstat-Walker forcing: loose early (damped steps), tight late
        const float eta   = fminf(0.3f, fmaxf(0.01f, lk));
        const float rztol = eta * eta;

        // ---- Chronopoulos-Gear PCG on h = Qh + diag(ex), scaled RHS ----
        float rs0 = u0 * sigma, rs1 = u1 * sigma;
        float z0  = rs0 * ih0,  z1  = rs1 * ih1;
        float dk0 = 0.f, dk1 = 0.f, pp0 = 0.f, pp1 = 0.f, sa0 = 0.f, sa1 = 0.f;
        float alpha = 1.f, rzp = 1.f, rz0v = 0.f;
        s_v[lane] = pk_rtn(z0, z1);
        asm volatile("" ::: "memory");

        for (int cg = 0; cg < 16; ++cg) {
            float ac0a=0.f, ac0b=0.f, ac1a=0.f, ac1b=0.f;
#define MVI(c,X0,X1) { const uint4 _V = vp[c];                                 \
    DOTG(a##c##_0,_V.x,X0) DOTG(a##c##_1,_V.y,X0)                              \
    DOTG(a##c##_2,_V.z,X0) DOTG(a##c##_3,_V.w,X0)                              \
    DOTG(b##c##_0,_V.x,X1) DOTG(b##c##_1,_V.y,X1)                              \
    DOTG(b##c##_2,_V.z,X1) DOTG(b##c##_3,_V.w,X1) }
            MVI(0,ac0a,ac1a)  MVI(1,ac0b,ac1b)  MVI(2,ac0a,ac1a)  MVI(3,ac0b,ac1b)
            MVI(4,ac0a,ac1a)  MVI(5,ac0b,ac1b)  MVI(6,ac0a,ac1a)  MVI(7,ac0b,ac1b)
            MVI(8,ac0a,ac1a)  MVI(9,ac0b,ac1b)  MVI(10,ac0a,ac1a) MVI(11,ac0b,ac1b)
            MVI(12,ac0a,ac1a) MVI(13,ac0b,ac1b) MVI(14,ac0a,ac1a) MVI(15,ac0b,ac1b)
#undef MVI
            const float w0 = fmaf(ex0, z0, ac0a + ac0b);  // h z
            const float w1 = fmaf(ex1, z1, ac1a + ac1b);

            float pr = fmaf(rs0, z0, rs1 * z1);      // rz
            float pd = fmaf(z0,  w0, z1  * w1);      // z.hz
            WSUM(pr); WSUM(pd);
            if (cg == 0) { rz0v = pr; if (rz0v <= 1e-30f) break; }
            else if (pr <= rztol * rz0v || pr <= 1e-32f) break;   // EW tol
            const float beta = (cg == 0) ? 0.0f : pr / rzp;
            const float pAp  = pd - beta * pr / alpha;
            alpha = pr / pAp;
            pp0 = fmaf(beta, pp0, z0);  pp1 = fmaf(beta, pp1, z1);
            sa0 = fmaf(beta, sa0, w0);  sa1 = fmaf(beta, sa1, w1);   // h p
            dk0 = fmaf(alpha, pp0, dk0); dk1 = fmaf(alpha, pp1, dk1);
            rs0 = fmaf(-alpha, sa0, rs0); rs1 = fmaf(-alpha, sa1, rs1);
            z0 = rs0 * ih0;  z1 = rs1 * ih1;
            rzp = pr;
            s_v[lane] = pk_rtn(z0, z1);              // republish
            asm volatile("" ::: "memory");
        }
        const float dku0 = dk0 * umax, dku1 = dk1 * umax;   // unscale

        // ---- damping / bookkeeping (exact reference logic, fp32) ----
        float gp = fmaxf(fabsf(dku0 / xv0), fabsf(dku1 / xv1));
        float sp = fmaf(dku0, u0, dku1 * u1);
        WMAX(gp); WSUM(sp);
        const float gk     = (lk <= FLc) ? 0.0f : gp;
        const float lk_new = sqrtf(fmaxf(sp, 0.0f));
        const float damp   = 1.0f / (1.0f + gk);
        xv0 -= dku0 * damp;
        xv1 -= dku1 * damp;
        // ---- qx recurrence: Qh*dku = u - umax*rs - ex.*dku (CG invariant) ----
        qx0 -= damp * (u0 - umax * rs0 - ex0 * dku0);
        qx1 -= damp * (u1 - umax * rs1 - ex1 * dku1);
        lk = lk_new;
        if (lk_new < 1e-4f) break;     // remaining motion <= 1e-4 -> out ~4e-6
    }

    // ---- normalize: x / (sum|x| + 1e-8) ----
    float sab = fabsf(xv0) + fabsf(xv1);
    WSUM(sab);
    const float inv = 1.0f / (sab + 1e-8f);
    ((float2*)(out + (size_t)b * NDIM))[lane] = make_float2(xv0 * inv, xv1 * inv);
}

extern "C" void kernel_launch(void* const* d_in, const int* in_sizes, int n_in,
                              void* d_out, int out_size, void* d_ws, size_t ws_size,
                              hipStream_t stream) {
    const float* Q = (const float*)d_in[0];
    const float* R = (const float*)d_in[1];
    float* out     = (float*)d_out;
    const int B    = in_sizes[1] / NDIM;   // 4096
    rpth_kernel<<<dim3(B), dim3(64), 0, stream>>>(Q, R, out);
}